// Round 7
// baseline (247.457 us; speedup 1.0000x reference)
//
#include <hip/hip_runtime.h>
#include <hip/hip_bf16.h>
#include <stdint.h>

// Problem constants (from reference)
#define N_NODES 50000
#define R_REL   4
#define E_EDGES 150000
#define E_TOT   600000      // R * E
#define DIM     128
#define K_TOT   512         // R * DIM
#define M_PAD   50048       // 391 * 128  (ceil(N/128)*128)
#define NB      200000      // N * R buckets
#define NC      8           // histogram privatization copies (~per-XCD)
#define BM      128
#define BK      64
#define EBLK    2344        // ceil(E_TOT/256)
#define PBLK    512         // 2*DIM*K_TOT/256 (prep_w blocks)

typedef __attribute__((ext_vector_type(4))) float f32x4;
typedef __attribute__((ext_vector_type(8))) short short8;
typedef __attribute__((ext_vector_type(4))) short s16x4;

__device__ __forceinline__ short f2bf(float f) {
    union { float f; unsigned u; } x{f};
    unsigned r = (x.u + 0x7fffu + ((x.u >> 16) & 1u)) >> 16;
    return (short)r;
}

// ---------------- edge histograms (privatized 8-way) + weight prep ----------
// blocks [0, EBLK): histogram edges; blocks [EBLK, EBLK+PBLK): transpose+cvt W
__global__ void hist_prep(const int* __restrict__ src, const int* __restrict__ dst,
                          int* __restrict__ cnt_src, int* __restrict__ cnt_dst,
                          const float* __restrict__ W1, const float* __restrict__ b1,
                          const float* __restrict__ W2, const float* __restrict__ b2,
                          short* __restrict__ Wt1, short* __restrict__ Wt2,
                          float* __restrict__ bias1, float* __restrict__ bias2) {
    if (blockIdx.x < EBLK) {
        int i = blockIdx.x * 256 + threadIdx.x;
        if (i >= E_TOT) return;
        int c = blockIdx.x & (NC - 1);
        int r = i / E_EDGES;
        atomicAdd(&cnt_src[c * NB + src[i] * 4 + r], 1);
        atomicAdd(&cnt_dst[c * NB + dst[i] * 4 + r], 1);
    } else {
        int i = (blockIdx.x - EBLK) * 256 + threadIdx.x;   // [0, 2*DIM*K_TOT)
        int layer = i >= DIM * K_TOT;
        int j = i - layer * DIM * K_TOT;
        const float* W = layer ? W2 : W1;
        short* Wt = layer ? Wt2 : Wt1;
        int o = j / K_TOT, k = j % K_TOT;                  // k = r*128 + d
        Wt[j] = f2bf(W[(size_t)k * DIM + o]);
        if (j < DIM) {
            const float* b = layer ? b2 : b1;
            float* bias = layer ? bias2 : bias1;
            float s = 0.f;
            for (int r = 0; r < R_REL; ++r) s += b[r * DIM + j];
            bias[j] = s;
        }
    }
}

// ---------------- scan1 (fused degree finalize): per-block exclusive scan ---
__global__ void scan1(const int* __restrict__ cnt_src, const int* __restrict__ cnt_dst,
                      float* __restrict__ rs_out, float* __restrict__ rs_in,
                      int* __restrict__ row_ptr, int* __restrict__ partials) {
    __shared__ int sh[256];
    int tid = threadIdx.x;
    int i = blockIdx.x * 256 + tid;
    int v = 0;
    if (i < NB) {
        int s1 = 0;
#pragma unroll
        for (int c = 0; c < NC; ++c) { v += cnt_dst[c * NB + i]; s1 += cnt_src[c * NB + i]; }
        int node = i >> 2, r = i & 3;
        rs_out[r * N_NODES + node] = rsqrtf(fmaxf((float)s1, 1.0f));
        rs_in [r * N_NODES + node] = rsqrtf(fmaxf((float)v,  1.0f));
    }
    sh[tid] = v;
    __syncthreads();
#pragma unroll
    for (int off = 1; off < 256; off <<= 1) {
        int t2 = (tid >= off) ? sh[tid - off] : 0;
        __syncthreads();
        sh[tid] += t2;
        __syncthreads();
    }
    if (i < NB) row_ptr[i] = sh[tid] - v;      // exclusive
    if (tid == 255) partials[blockIdx.x] = sh[255];
}

__global__ void scan2(int* __restrict__ partials, int nb) {
    __shared__ int sh[1024];
    int tid = threadIdx.x;
    int v = (tid < nb) ? partials[tid] : 0;
    sh[tid] = v;
    __syncthreads();
    for (int off = 1; off < 1024; off <<= 1) {
        int t2 = (tid >= off) ? sh[tid - off] : 0;
        __syncthreads();
        sh[tid] += t2;
        __syncthreads();
    }
    if (tid < nb) partials[tid] = sh[tid] - v;  // exclusive
}

// scan3: add block offsets; convert per-copy counts -> per-copy exclusive bases
__global__ void scan3(int* __restrict__ row_ptr, const int* __restrict__ partials,
                      int* __restrict__ cnt_dst) {
    int i = blockIdx.x * 256 + threadIdx.x;
    if (i < NB) {
        row_ptr[i] += partials[i >> 8];
        int run = 0;
#pragma unroll
        for (int c = 0; c < NC; ++c) {
            int v = cnt_dst[c * NB + i];
            cnt_dst[c * NB + i] = run;
            run += v;
        }
    }
    if (i == 0) row_ptr[NB] = E_TOT;
}

// ---------------- fill CSR edge records {src, rs_out[r][src]} ----------------
__global__ void fill_csr(const int* __restrict__ src, const int* __restrict__ dst,
                         const int* __restrict__ row_ptr, int* __restrict__ base_cur,
                         const float* __restrict__ rs_out, int2* __restrict__ erec) {
    int i = blockIdx.x * 256 + threadIdx.x;
    if (i < 4) { int2 z; z.x = 0; z.y = 0; erec[E_TOT + i] = z; }  // slack for chunk-4 reads
    if (i >= E_TOT) return;
    int c = blockIdx.x & (NC - 1);              // same mapping as hist
    int r = i / E_EDGES;
    int s = src[i], d = dst[i];
    int b = d * 4 + r;
    int pos = row_ptr[b] + atomicAdd(&base_cur[c * NB + b], 1);
    int2 rec;
    rec.x = s;
    rec.y = __float_as_int(rs_out[r * N_NODES + s]);
    erec[pos] = rec;
}

// ---------------- gather: agg[d][r*128+:] = rs_in * sum_e w_e * h[src_e][:] (bf16 out)
// 32 lanes per (dst,r) pair. Chunk-of-4 edges: records fetched via uniform
// int2 loads (broadcast, L2-resident) -> no shuffles; tail edges read slack /
// next-bucket records (valid src) with weight masked to 0 -> no per-lane
// predication. h is f32 for both layers (no bf16 converts in the hot loop).
__global__ void gather_edges(const int* __restrict__ row_ptr, const int2* __restrict__ erec,
                             const float* __restrict__ rs_in, const float* __restrict__ h,
                             short* __restrict__ agg) {
    int t = blockIdx.x * blockDim.x + threadIdx.x;
    int pair = t >> 5;               // 32 lanes per (dst, r) pair
    if (pair >= NB) return;
    int lane = t & 31;
    int d = pair >> 2, r = pair & 3;
    int beg = row_ptr[pair], end = row_ptr[pair + 1];
    f32x4 acc = {0.f, 0.f, 0.f, 0.f};
    for (int e0 = beg; e0 < end; e0 += 4) {
        int2 q0 = erec[e0 + 0];
        int2 q1 = erec[e0 + 1];
        int2 q2 = erec[e0 + 2];
        int2 q3 = erec[e0 + 3];
        f32x4 v0 = *((const f32x4*)(h + (size_t)q0.x * DIM) + lane);
        f32x4 v1 = *((const f32x4*)(h + (size_t)q1.x * DIM) + lane);
        f32x4 v2 = *((const f32x4*)(h + (size_t)q2.x * DIM) + lane);
        f32x4 v3 = *((const f32x4*)(h + (size_t)q3.x * DIM) + lane);
        float w0 = __int_as_float(q0.y);
        float w1 = (e0 + 1 < end) ? __int_as_float(q1.y) : 0.f;
        float w2 = (e0 + 2 < end) ? __int_as_float(q2.y) : 0.f;
        float w3 = (e0 + 3 < end) ? __int_as_float(q3.y) : 0.f;
        acc += v0 * w0;
        acc += v1 * w1;
        acc += v2 * w2;
        acc += v3 * w3;
    }
    acc *= rs_in[r * N_NODES + d];
    s16x4 o;
    o[0] = f2bf(acc[0]); o[1] = f2bf(acc[1]); o[2] = f2bf(acc[2]); o[3] = f2bf(acc[3]);
    *((s16x4*)(agg + (size_t)d * K_TOT + r * DIM) + lane) = o;
}

// ---------------- GEMM: out[M,128] = A[M,512](bf16) @ Wt^T + bias ------------
template <bool RELU>
__global__ __launch_bounds__(256, 2)
void gemm_kernel(const short* __restrict__ A, const short* __restrict__ Wt,
                 const float* __restrict__ bias, float* __restrict__ out) {
    __shared__ short a_sh[128 * 72];   // [row][k], padded stride 72
    __shared__ short b_sh[128 * 72];   // [col][k], padded stride 72

    const int tid  = threadIdx.x;
    const int bm0  = blockIdx.x * BM;
    const int lane = tid & 63;
    const int wid  = tid >> 6;
    const int wm   = wid >> 1, wn = wid & 1;   // 2x2 waves of 64x64
    const int l15  = lane & 15, l4 = lane >> 4;

    f32x4 acc[4][4] = {};

    for (int kk = 0; kk < K_TOT; kk += BK) {
        __syncthreads();
#pragma unroll
        for (int j = 0; j < 4; ++j) {
            int c = tid + 256 * j;
            int row = c >> 3, ku = c & 7;
            *(short8*)&a_sh[row * 72 + ku * 8] =
                *(const short8*)(A + (size_t)(bm0 + row) * K_TOT + kk + ku * 8);
        }
#pragma unroll
        for (int j = 0; j < 4; ++j) {
            int c = tid + 256 * j;
            int col = c >> 3, ku = c & 7;
            *(short8*)&b_sh[col * 72 + ku * 8] =
                *(const short8*)(Wt + (size_t)col * K_TOT + kk + ku * 8);
        }
        __syncthreads();
#pragma unroll
        for (int ki = 0; ki < 2; ++ki) {
            short8 a[4], b[4];
            int ku = ki * 4 + l4;
#pragma unroll
            for (int f = 0; f < 4; ++f) {
                int row = wm * 64 + f * 16 + l15;
                a[f] = *(const short8*)&a_sh[row * 72 + ku * 8];
                int col = wn * 64 + f * 16 + l15;
                b[f] = *(const short8*)&b_sh[col * 72 + ku * 8];
            }
#pragma unroll
            for (int fm = 0; fm < 4; ++fm)
#pragma unroll
                for (int fn = 0; fn < 4; ++fn)
                    acc[fm][fn] = __builtin_amdgcn_mfma_f32_16x16x32_bf16(
                        a[fm], b[fn], acc[fm][fn], 0, 0, 0);
        }
    }

    // epilogue: D mapping col = lane&15, row = (lane>>4)*4 + reg
#pragma unroll
    for (int fn = 0; fn < 4; ++fn) {
        int col = wn * 64 + fn * 16 + l15;
        float bi = bias[col];
#pragma unroll
        for (int fm = 0; fm < 4; ++fm) {
            int row0 = bm0 + wm * 64 + fm * 16 + l4 * 4;
#pragma unroll
            for (int rr = 0; rr < 4; ++rr) {
                int row = row0 + rr;
                if (row < N_NODES) {
                    float v = acc[fm][fn][rr] + bi;
                    if (RELU) v = fmaxf(v, 0.f);
                    out[(size_t)row * DIM + col] = v;
                }
            }
        }
    }
}

// ---------------- launcher ----------------
extern "C" void kernel_launch(void* const* d_in, const int* in_sizes, int n_in,
                              void* d_out, int out_size, void* d_ws, size_t ws_size,
                              hipStream_t stream) {
    const float* x    = (const float*)d_in[0];
    const int*   esrc = (const int*)  d_in[1];
    const int*   edst = (const int*)  d_in[2];
    const float* W1   = (const float*)d_in[3];
    const float* b1   = (const float*)d_in[4];
    const float* W2   = (const float*)d_in[5];
    const float* b2   = (const float*)d_in[6];
    float* out = (float*)d_out;
    char*  ws  = (char*)d_ws;

    // workspace layout (bytes), ~97.1 MB total:
    float* rs      = (float*)ws;                    // rs_out[R*N] + rs_in[R*N] -> 1,600,000
    float* rs_out  = rs;
    float* rs_in   = rs + R_REL * N_NODES;
    float* bias1   = (float*)(ws + 1600000);        // 512
    float* bias2   = (float*)(ws + 1600512);        // 512
    short* Wt1     = (short*)(ws + 1601024);        // 131,072
    short* Wt2     = (short*)(ws + 1732096);        // 131,072 -> 1,863,168
    float* h       = (float*)(ws + 1863168);        // f32 [N][128] 25,600,000 -> 27,463,168
    short* agg     = (short*)(ws + 27463168);       // bf16 [M_PAD][512] 51,249,152 -> 78,712,320
    int*   cnt_src = (int*)  (ws + 78712320);       // [NC][NB] 6,400,000 -> 85,112,320
    int*   cnt_dst = (int*)  (ws + 85112320);       // [NC][NB] 6,400,000 -> 91,512,320
    int*   rowptr  = (int*)  (ws + 91512320);       // 800,064 -> 92,312,384
    int*   parts   = (int*)  (ws + 92312384);       // 4,096   -> 92,316,480
    int2*  erec    = (int2*) (ws + 92316480);       // (E_TOT+4)*8 = 4,800,032 -> 97,116,512

    // zero the two histogram arrays (contiguous 12.8 MB)
    hipMemsetAsync(cnt_src, 0, 2 * 6400000, stream);

    // histogram + weight prep in one launch
    hist_prep<<<EBLK + PBLK, 256, 0, stream>>>(esrc, edst, cnt_src, cnt_dst,
                                               W1, b1, W2, b2, Wt1, Wt2, bias1, bias2);

    const int nb_blk = (NB + 255) / 256;            // 782
    scan1<<<nb_blk, 256, 0, stream>>>(cnt_src, cnt_dst, rs_out, rs_in, rowptr, parts);
    scan2<<<1, 1024, 0, stream>>>(parts, nb_blk);
    scan3<<<nb_blk, 256, 0, stream>>>(rowptr, parts, cnt_dst);

    fill_csr<<<EBLK, 256, 0, stream>>>(esrc, edst, rowptr, cnt_dst, rs_out, erec);

    const int gat_blocks = (NB * 32) / 256;         // 25,000
    const int gemm_blocks = M_PAD / BM;             // 391

    // ---- layer 1 ----
    gather_edges<<<gat_blocks, 256, 0, stream>>>(rowptr, erec, rs_in, x, agg);
    gemm_kernel<true><<<gemm_blocks, 256, 0, stream>>>(agg, Wt1, bias1, h);

    // ---- layer 2 ----
    gather_edges<<<gat_blocks, 256, 0, stream>>>(rowptr, erec, rs_in, h, agg);
    gemm_kernel<false><<<gemm_blocks, 256, 0, stream>>>(agg, Wt2, bias2, out);
}

// Round 8
// 245.891 us; speedup vs baseline: 1.0064x; 1.0064x over previous
//
#include <hip/hip_runtime.h>
#include <hip/hip_bf16.h>
#include <stdint.h>

// Problem constants (from reference)
#define N_NODES 50000
#define R_REL   4
#define E_EDGES 150000
#define E_TOT   600000      // R * E
#define DIM     128
#define K_TOT   512         // R * DIM
#define M_PAD   50048       // 391 * 128  (ceil(N/128)*128)
#define NB      200000      // N * R buckets
#define NC      8           // histogram privatization copies (~per-XCD)
#define BM      128
#define BK      64
#define EBLK    2344        // ceil(E_TOT/256)
#define PBLK    512         // 2*DIM*K_TOT/256 (prep_w blocks)

typedef __attribute__((ext_vector_type(4))) float f32x4;
typedef __attribute__((ext_vector_type(8))) short short8;
typedef __attribute__((ext_vector_type(4))) short s16x4;

__device__ __forceinline__ short f2bf(float f) {
    union { float f; unsigned u; } x{f};
    unsigned r = (x.u + 0x7fffu + ((x.u >> 16) & 1u)) >> 16;
    return (short)r;
}

// ---------------- edge histograms (privatized 8-way) + weight prep ----------
__global__ void hist_prep(const int* __restrict__ src, const int* __restrict__ dst,
                          int* __restrict__ cnt_src, int* __restrict__ cnt_dst,
                          const float* __restrict__ W1, const float* __restrict__ b1,
                          const float* __restrict__ W2, const float* __restrict__ b2,
                          short* __restrict__ Wt1, short* __restrict__ Wt2,
                          float* __restrict__ bias1, float* __restrict__ bias2) {
    if (blockIdx.x < EBLK) {
        int i = blockIdx.x * 256 + threadIdx.x;
        if (i >= E_TOT) return;
        int c = blockIdx.x & (NC - 1);
        int r = i / E_EDGES;
        atomicAdd(&cnt_src[c * NB + src[i] * 4 + r], 1);
        atomicAdd(&cnt_dst[c * NB + dst[i] * 4 + r], 1);
    } else {
        int i = (blockIdx.x - EBLK) * 256 + threadIdx.x;   // [0, 2*DIM*K_TOT)
        int layer = i >= DIM * K_TOT;
        int j = i - layer * DIM * K_TOT;
        const float* W = layer ? W2 : W1;
        short* Wt = layer ? Wt2 : Wt1;
        int o = j / K_TOT, k = j % K_TOT;                  // k = r*128 + d
        Wt[j] = f2bf(W[(size_t)k * DIM + o]);
        if (j < DIM) {
            const float* b = layer ? b2 : b1;
            float* bias = layer ? bias2 : bias1;
            float s = 0.f;
            for (int r = 0; r < R_REL; ++r) s += b[r * DIM + j];
            bias[j] = s;
        }
    }
}

// ---------------- scan1 (fused degree finalize): per-block exclusive scan ---
// rs arrays are in BUCKET layout: rs[node*4 + r]
__global__ void scan1(const int* __restrict__ cnt_src, const int* __restrict__ cnt_dst,
                      float* __restrict__ rs_out, float* __restrict__ rs_in,
                      int* __restrict__ row_ptr, int* __restrict__ partials) {
    __shared__ int sh[256];
    int tid = threadIdx.x;
    int i = blockIdx.x * 256 + tid;
    int v = 0;
    if (i < NB) {
        int s1 = 0;
#pragma unroll
        for (int c = 0; c < NC; ++c) { v += cnt_dst[c * NB + i]; s1 += cnt_src[c * NB + i]; }
        rs_out[i] = rsqrtf(fmaxf((float)s1, 1.0f));
        rs_in [i] = rsqrtf(fmaxf((float)v,  1.0f));
    }
    sh[tid] = v;
    __syncthreads();
#pragma unroll
    for (int off = 1; off < 256; off <<= 1) {
        int t2 = (tid >= off) ? sh[tid - off] : 0;
        __syncthreads();
        sh[tid] += t2;
        __syncthreads();
    }
    if (i < NB) row_ptr[i] = sh[tid] - v;      // exclusive
    if (tid == 255) partials[blockIdx.x] = sh[255];
}

__global__ void scan2(int* __restrict__ partials, int nb) {
    __shared__ int sh[1024];
    int tid = threadIdx.x;
    int v = (tid < nb) ? partials[tid] : 0;
    sh[tid] = v;
    __syncthreads();
    for (int off = 1; off < 1024; off <<= 1) {
        int t2 = (tid >= off) ? sh[tid - off] : 0;
        __syncthreads();
        sh[tid] += t2;
        __syncthreads();
    }
    if (tid < nb) partials[tid] = sh[tid] - v;  // exclusive
}

// scan3: add block offsets; convert per-copy counts -> per-copy exclusive bases
__global__ void scan3(int* __restrict__ row_ptr, const int* __restrict__ partials,
                      int* __restrict__ cnt_dst) {
    int i = blockIdx.x * 256 + threadIdx.x;
    if (i < NB) {
        row_ptr[i] += partials[i >> 8];
        int run = 0;
#pragma unroll
        for (int c = 0; c < NC; ++c) {
            int v = cnt_dst[c * NB + i];
            cnt_dst[c * NB + i] = run;
            run += v;
        }
    }
    if (i == 0) row_ptr[NB] = E_TOT;
}

// ---------------- fill CSR edge records {src, rs_out[src*4+r]} --------------
__global__ void fill_csr(const int* __restrict__ src, const int* __restrict__ dst,
                         const int* __restrict__ row_ptr, int* __restrict__ base_cur,
                         const float* __restrict__ rs_out, int2* __restrict__ erec) {
    int i = blockIdx.x * 256 + threadIdx.x;
    if (i < 4) { int2 z; z.x = 0; z.y = 0; erec[E_TOT + i] = z; }  // slack for chunk-4 reads
    if (i >= E_TOT) return;
    int c = blockIdx.x & (NC - 1);              // same mapping as hist
    int r = i / E_EDGES;
    int s = src[i], d = dst[i];
    int b = d * 4 + r;
    int pos = row_ptr[b] + atomicAdd(&base_cur[c * NB + b], 1);
    int2 rec;
    rec.x = s;
    rec.y = __float_as_int(rs_out[s * 4 + r]);
    erec[pos] = rec;
}

// ---------------- gather: one 32-lane group per DST NODE (4 pairs = 4 rels) -
// 4x MLP: 16 independent h-row loads in flight per group; one int4 rowptr
// load; 4 contiguous bf16 stores into one agg row. Tail (deg>4, ~18%) via
// per-relation chunk-4 loop.
__global__ void gather_edges(const int* __restrict__ row_ptr, const int2* __restrict__ erec,
                             const float* __restrict__ rs_in, const float* __restrict__ h,
                             short* __restrict__ agg) {
    int t = blockIdx.x * blockDim.x + threadIdx.x;
    int d = t >> 5;                  // 32 lanes per dst node (4 buckets)
    if (d >= N_NODES) return;
    int lane = t & 31;
    int p0 = d * 4;

    // phase 0: bucket boundaries (one aligned int4 + one int)
    int4 rp = *(const int4*)(row_ptr + p0);
    int  rp4 = row_ptr[p0 + 4];
    int beg[4] = {rp.x, rp.y, rp.z, rp.w};
    int end[4] = {rp.y, rp.z, rp.w, rp4};

    // phase 1: 16 independent edge-record loads (slack-protected)
    int2 q[4][4];
#pragma unroll
    for (int k = 0; k < 4; ++k)
#pragma unroll
        for (int j = 0; j < 4; ++j)
            q[k][j] = erec[beg[k] + j];

    // phase 2: 16 independent h-row loads
    f32x4 v[4][4];
#pragma unroll
    for (int k = 0; k < 4; ++k)
#pragma unroll
        for (int j = 0; j < 4; ++j)
            v[k][j] = *((const f32x4*)(h + (size_t)q[k][j].x * DIM) + lane);

    // phase 3: masked FMAs
    f32x4 acc[4] = {};
#pragma unroll
    for (int k = 0; k < 4; ++k)
#pragma unroll
        for (int j = 0; j < 4; ++j) {
            float w = (beg[k] + j < end[k]) ? __int_as_float(q[k][j].y) : 0.f;
            acc[k] += v[k][j] * w;
        }

    // tail: buckets with deg > 4 (uniform branch per relation)
#pragma unroll
    for (int k = 0; k < 4; ++k) {
        for (int e0 = beg[k] + 4; e0 < end[k]; e0 += 4) {
            int2 t0 = erec[e0 + 0];
            int2 t1 = erec[e0 + 1];
            int2 t2 = erec[e0 + 2];
            int2 t3 = erec[e0 + 3];
            f32x4 u0 = *((const f32x4*)(h + (size_t)t0.x * DIM) + lane);
            f32x4 u1 = *((const f32x4*)(h + (size_t)t1.x * DIM) + lane);
            f32x4 u2 = *((const f32x4*)(h + (size_t)t2.x * DIM) + lane);
            f32x4 u3 = *((const f32x4*)(h + (size_t)t3.x * DIM) + lane);
            float w0 = __int_as_float(t0.y);
            float w1 = (e0 + 1 < end[k]) ? __int_as_float(t1.y) : 0.f;
            float w2 = (e0 + 2 < end[k]) ? __int_as_float(t2.y) : 0.f;
            float w3 = (e0 + 3 < end[k]) ? __int_as_float(t3.y) : 0.f;
            acc[k] += u0 * w0;
            acc[k] += u1 * w1;
            acc[k] += u2 * w2;
            acc[k] += u3 * w3;
        }
    }

    // phase 4: scale by dest norms (one f32x4, bucket layout) + 4 stores
    f32x4 rs4 = *(const f32x4*)(rs_in + p0);
#pragma unroll
    for (int k = 0; k < 4; ++k) {
        f32x4 a = acc[k] * rs4[k];
        s16x4 o;
        o[0] = f2bf(a[0]); o[1] = f2bf(a[1]); o[2] = f2bf(a[2]); o[3] = f2bf(a[3]);
        *((s16x4*)(agg + (size_t)d * K_TOT + k * DIM) + lane) = o;
    }
}

// ---------------- GEMM: out[M,128] = A[M,512](bf16) @ Wt^T + bias ------------
template <bool RELU>
__global__ __launch_bounds__(256, 2)
void gemm_kernel(const short* __restrict__ A, const short* __restrict__ Wt,
                 const float* __restrict__ bias, float* __restrict__ out) {
    __shared__ short a_sh[128 * 72];   // [row][k], padded stride 72
    __shared__ short b_sh[128 * 72];   // [col][k], padded stride 72

    const int tid  = threadIdx.x;
    const int bm0  = blockIdx.x * BM;
    const int lane = tid & 63;
    const int wid  = tid >> 6;
    const int wm   = wid >> 1, wn = wid & 1;   // 2x2 waves of 64x64
    const int l15  = lane & 15, l4 = lane >> 4;

    f32x4 acc[4][4] = {};

    for (int kk = 0; kk < K_TOT; kk += BK) {
        __syncthreads();
#pragma unroll
        for (int j = 0; j < 4; ++j) {
            int c = tid + 256 * j;
            int row = c >> 3, ku = c & 7;
            *(short8*)&a_sh[row * 72 + ku * 8] =
                *(const short8*)(A + (size_t)(bm0 + row) * K_TOT + kk + ku * 8);
        }
#pragma unroll
        for (int j = 0; j < 4; ++j) {
            int c = tid + 256 * j;
            int col = c >> 3, ku = c & 7;
            *(short8*)&b_sh[col * 72 + ku * 8] =
                *(const short8*)(Wt + (size_t)col * K_TOT + kk + ku * 8);
        }
        __syncthreads();
#pragma unroll
        for (int ki = 0; ki < 2; ++ki) {
            short8 a[4], b[4];
            int ku = ki * 4 + l4;
#pragma unroll
            for (int f = 0; f < 4; ++f) {
                int row = wm * 64 + f * 16 + l15;
                a[f] = *(const short8*)&a_sh[row * 72 + ku * 8];
                int col = wn * 64 + f * 16 + l15;
                b[f] = *(const short8*)&b_sh[col * 72 + ku * 8];
            }
#pragma unroll
            for (int fm = 0; fm < 4; ++fm)
#pragma unroll
                for (int fn = 0; fn < 4; ++fn)
                    acc[fm][fn] = __builtin_amdgcn_mfma_f32_16x16x32_bf16(
                        a[fm], b[fn], acc[fm][fn], 0, 0, 0);
        }
    }

    // epilogue: D mapping col = lane&15, row = (lane>>4)*4 + reg
#pragma unroll
    for (int fn = 0; fn < 4; ++fn) {
        int col = wn * 64 + fn * 16 + l15;
        float bi = bias[col];
#pragma unroll
        for (int fm = 0; fm < 4; ++fm) {
            int row0 = bm0 + wm * 64 + fm * 16 + l4 * 4;
#pragma unroll
            for (int rr = 0; rr < 4; ++rr) {
                int row = row0 + rr;
                if (row < N_NODES) {
                    float v = acc[fm][fn][rr] + bi;
                    if (RELU) v = fmaxf(v, 0.f);
                    out[(size_t)row * DIM + col] = v;
                }
            }
        }
    }
}

// ---------------- launcher ----------------
extern "C" void kernel_launch(void* const* d_in, const int* in_sizes, int n_in,
                              void* d_out, int out_size, void* d_ws, size_t ws_size,
                              hipStream_t stream) {
    const float* x    = (const float*)d_in[0];
    const int*   esrc = (const int*)  d_in[1];
    const int*   edst = (const int*)  d_in[2];
    const float* W1   = (const float*)d_in[3];
    const float* b1   = (const float*)d_in[4];
    const float* W2   = (const float*)d_in[5];
    const float* b2   = (const float*)d_in[6];
    float* out = (float*)d_out;
    char*  ws  = (char*)d_ws;

    // workspace layout (bytes), ~97.1 MB total:
    float* rs      = (float*)ws;                    // rs_out[NB] + rs_in[NB] (bucket layout)
    float* rs_out  = rs;
    float* rs_in   = rs + NB;
    float* bias1   = (float*)(ws + 1600000);        // 512
    float* bias2   = (float*)(ws + 1600512);        // 512
    short* Wt1     = (short*)(ws + 1601024);        // 131,072
    short* Wt2     = (short*)(ws + 1732096);        // 131,072 -> 1,863,168
    float* h       = (float*)(ws + 1863168);        // f32 [N][128] 25,600,000 -> 27,463,168
    short* agg     = (short*)(ws + 27463168);       // bf16 [M_PAD][512] 51,249,152 -> 78,712,320
    int*   cnt_src = (int*)  (ws + 78712320);       // [NC][NB] 6,400,000 -> 85,112,320
    int*   cnt_dst = (int*)  (ws + 85112320);       // [NC][NB] 6,400,000 -> 91,512,320
    int*   rowptr  = (int*)  (ws + 91512320);       // 800,064 -> 92,312,384
    int*   parts   = (int*)  (ws + 92312384);       // 4,096   -> 92,316,480
    int2*  erec    = (int2*) (ws + 92316480);       // (E_TOT+4)*8 = 4,800,032 -> 97,116,512

    // zero the two histogram arrays (contiguous 12.8 MB)
    hipMemsetAsync(cnt_src, 0, 2 * 6400000, stream);

    // histogram + weight prep in one launch
    hist_prep<<<EBLK + PBLK, 256, 0, stream>>>(esrc, edst, cnt_src, cnt_dst,
                                               W1, b1, W2, b2, Wt1, Wt2, bias1, bias2);

    const int nb_blk = (NB + 255) / 256;            // 782
    scan1<<<nb_blk, 256, 0, stream>>>(cnt_src, cnt_dst, rs_out, rs_in, rowptr, parts);
    scan2<<<1, 1024, 0, stream>>>(parts, nb_blk);
    scan3<<<nb_blk, 256, 0, stream>>>(rowptr, parts, cnt_dst);

    fill_csr<<<EBLK, 256, 0, stream>>>(esrc, edst, rowptr, cnt_dst, rs_out, erec);

    const int gat_blocks = (N_NODES * 32 + 255) / 256;  // 6,250
    const int gemm_blocks = M_PAD / BM;                 // 391

    // ---- layer 1 ----
    gather_edges<<<gat_blocks, 256, 0, stream>>>(rowptr, erec, rs_in, x, agg);
    gemm_kernel<true><<<gemm_blocks, 256, 0, stream>>>(agg, Wt1, bias1, h);

    // ---- layer 2 ----
    gather_edges<<<gat_blocks, 256, 0, stream>>>(rowptr, erec, rs_in, h, agg);
    gemm_kernel<false><<<gemm_blocks, 256, 0, stream>>>(agg, Wt2, bias2, out);
}